// Round 2
// baseline (9.695 us; speedup 1.0000x reference)
//
#include <hip/hip_runtime.h>

// ELBO: out[b] = -sum_c log(decoded[b, ctx[b,c]]) + sum_e KL_term(b,e)
// B=4096 CTX=20 EMBED=100 VOCAB=50000; all f32 except context (int32).
//
// Round 2: latency-bound (measured ~16% of achievable HBM BW at 9.36us).
// Split each example across TWO waves (50 embed dims + 10 gathers each):
// 8192 waves = 32 waves/CU = full occupancy (was 16/CU), doubling the
// outstanding-miss pool that hides the context->gather dependent chain.
// Block = 256 thr = 4 waves = 2 examples; combine partials via 16B LDS.

constexpr int B_     = 4096;
constexpr int CTX_   = 20;
constexpr int EMBED_ = 100;
constexpr int VOCAB_ = 50000;

__global__ __launch_bounds__(256) void elbo_kernel(
    const int*   __restrict__ context,       // [B, CTX]
    const float* __restrict__ mu_lambda,     // [B, EMBED]
    const float* __restrict__ sigma_lambda,  // [B, EMBED]
    const float* __restrict__ mu_x,          // [B, EMBED]
    const float* __restrict__ sigma_x,       // [B, EMBED]
    const float* __restrict__ decoded,       // [B, VOCAB]
    float*       __restrict__ out)           // [B]
{
    __shared__ float partial[4];

    const int tid  = (int)threadIdx.x;
    const int w    = tid >> 6;      // wave within block: 0..3
    const int lane = tid & 63;
    const int exL  = w >> 1;        // local example: 0..1
    const int half = w & 1;         // which half of the work
    const int b    = (int)blockIdx.x * 2 + exL;

    // Issue the context load FIRST: its latency overlaps the KL loads below,
    // shortening the context->gather dependent chain's exposed latency.
    int idx = 0;
    const bool do_gather = (lane < CTX_ / 2);            // lanes 0..9
    if (do_gather)
        idx = context[(size_t)b * CTX_ + half * (CTX_ / 2) + lane];

    float acc = 0.0f;

    // KL: this wave covers embed dims [half*50, half*50+50), lanes 0..49.
    if (lane < EMBED_ / 2) {
        const size_t eb = (size_t)b * EMBED_ + half * (EMBED_ / 2) + lane;
        float s_l = sigma_lambda[eb];
        float s_x = sigma_x[eb];
        float dmu = mu_lambda[eb] - mu_x[eb];
        float inv = __fdividef(1.0f, s_x);
        acc = __logf(s_x * __fdividef(1.0f, s_l))
            + (s_l * s_l + dmu * dmu) * 0.5f * inv * inv - 0.5f;
    }

    // Dependent gather: lanes 0..9 of each wave (10 of the 20 ctx words).
    if (do_gather) {
        float g = decoded[(size_t)b * VOCAB_ + idx];
        acc -= __logf(g);
    }

    // 64-lane butterfly reduce within the wave.
    #pragma unroll
    for (int off = 32; off > 0; off >>= 1)
        acc += __shfl_xor(acc, off, 64);

    if (lane == 0) partial[w] = acc;
    __syncthreads();

    // Threads 0,1 combine the two wave-halves of their example.
    if (tid < 2)
        out[(size_t)blockIdx.x * 2 + tid] = partial[2 * tid] + partial[2 * tid + 1];
}

extern "C" void kernel_launch(void* const* d_in, const int* in_sizes, int n_in,
                              void* d_out, int out_size, void* d_ws, size_t ws_size,
                              hipStream_t stream) {
    const int*   context      = (const int*)  d_in[0];
    const float* mu_lambda    = (const float*)d_in[1];
    const float* sigma_lambda = (const float*)d_in[2];
    const float* mu_x         = (const float*)d_in[3];
    const float* sigma_x      = (const float*)d_in[4];
    const float* decoded      = (const float*)d_in[5];
    float* out = (float*)d_out;

    // 2 examples per 256-thread block -> 2048 blocks = 8 blocks/CU = 32 waves/CU.
    const int threads = 256;
    const int blocks  = B_ / 2;  // 2048
    elbo_kernel<<<blocks, threads, 0, stream>>>(
        context, mu_lambda, sigma_lambda, mu_x, sigma_x, decoded, out);
}

// Round 3
// 9.674 us; speedup vs baseline: 1.0021x; 1.0021x over previous
//
#include <hip/hip_runtime.h>

// ELBO: out[b] = -sum_c log(decoded[b, ctx[b,c]]) + sum_e KL_term(b,e)
// B=4096 CTX=20 EMBED=100 VOCAB=50000; all f32 except context (int32).
//
// Round 3: two structurally different kernels measured 9.36 / 9.69 us ->
// at the small-kernel dispatch/latency floor (~10 us per rocprof.md), not
// BW- or occupancy-bound. Final variant = best structure (1 wave/example)
// with minimal instruction stream:
//   lanes 0..24  : float4 KL loads (rows are 400B -> 16B aligned), 4 dims/lane
//   lanes 25..44 : context load -> dependent decoded gather (disjoint lanes,
//                  so gather chain overlaps KL loads with no lane contention)
//   butterfly reduce over 64 lanes, lane 0 writes out[b]. No LDS, no syncs.

constexpr int B_     = 4096;
constexpr int CTX_   = 20;
constexpr int EMBED_ = 100;
constexpr int VOCAB_ = 50000;

__global__ __launch_bounds__(256) void elbo_kernel(
    const int*   __restrict__ context,       // [B, CTX]
    const float* __restrict__ mu_lambda,     // [B, EMBED]
    const float* __restrict__ sigma_lambda,  // [B, EMBED]
    const float* __restrict__ mu_x,          // [B, EMBED]
    const float* __restrict__ sigma_x,       // [B, EMBED]
    const float* __restrict__ decoded,       // [B, VOCAB]
    float*       __restrict__ out)           // [B]
{
    const int wave = (int)((blockIdx.x * blockDim.x + threadIdx.x) >> 6);
    const int lane = (int)(threadIdx.x & 63);
    if (wave >= B_) return;

    const bool kl_lane = (lane < EMBED_ / 4);               // lanes 0..24
    const bool ga_lane = (lane >= 25 && lane < 25 + CTX_);  // lanes 25..44

    // Issue the context load first so the dependent gather's latency
    // overlaps the param loads issued just below.
    int idx = 0;
    if (ga_lane) idx = context[(size_t)wave * CTX_ + (lane - 25)];

    float acc = 0.0f;

    if (kl_lane) {
        const float4* mul4 = (const float4*)(mu_lambda    + (size_t)wave * EMBED_);
        const float4* sl4  = (const float4*)(sigma_lambda + (size_t)wave * EMBED_);
        const float4* mux4 = (const float4*)(mu_x         + (size_t)wave * EMBED_);
        const float4* sx4  = (const float4*)(sigma_x      + (size_t)wave * EMBED_);
        float4 ml = mul4[lane];
        float4 sl = sl4[lane];
        float4 mx = mux4[lane];
        float4 sx = sx4[lane];
        #pragma unroll
        for (int j = 0; j < 4; ++j) {
            float s_l = (&sl.x)[j], s_x = (&sx.x)[j];
            float dmu = (&ml.x)[j] - (&mx.x)[j];
            float inv = __fdividef(1.0f, s_x);
            acc += __logf(s_x * __fdividef(1.0f, s_l))
                 + (s_l * s_l + dmu * dmu) * 0.5f * inv * inv - 0.5f;
        }
    }

    if (ga_lane) {
        float g = decoded[(size_t)wave * VOCAB_ + idx];
        acc -= __logf(g);
    }

    // 64-lane butterfly reduce.
    #pragma unroll
    for (int off = 32; off > 0; off >>= 1)
        acc += __shfl_xor(acc, off, 64);

    if (lane == 0) out[wave] = acc;
}

extern "C" void kernel_launch(void* const* d_in, const int* in_sizes, int n_in,
                              void* d_out, int out_size, void* d_ws, size_t ws_size,
                              hipStream_t stream) {
    const int*   context      = (const int*)  d_in[0];
    const float* mu_lambda    = (const float*)d_in[1];
    const float* sigma_lambda = (const float*)d_in[2];
    const float* mu_x         = (const float*)d_in[3];
    const float* sigma_x      = (const float*)d_in[4];
    const float* decoded      = (const float*)d_in[5];
    float* out = (float*)d_out;

    const int threads = 256;                 // 4 waves/block
    const int blocks  = (B_ * 64) / threads; // 1024 blocks = 4096 waves
    elbo_kernel<<<blocks, threads, 0, stream>>>(
        context, mu_lambda, sigma_lambda, mu_x, sigma_x, decoded, out);
}